// Round 11
// baseline (3421.475 us; speedup 1.0000x reference)
//
#include <hip/hip_runtime.h>
#include <hip/hip_bf16.h>
#include <cstdint>
#include <cstddef>

#define DI __device__ __forceinline__
#define RLX __ATOMIC_RELAXED
#define AGT __HIP_MEMORY_SCOPE_AGENT
#define WGP __HIP_MEMORY_SCOPE_WORKGROUP

typedef __attribute__((ext_vector_type(8))) short          bf16x8;
typedef __attribute__((ext_vector_type(8))) unsigned short u16x8;
typedef __attribute__((ext_vector_type(4))) float          f32x4;
typedef __attribute__((ext_vector_type(4))) unsigned int   u32x4;

// ---- problem constants ----
constexpr int Sv = 512, Bv = 128, Dv = 512, Hv = 256;
constexpr int LMAX = 8;   // run-length cap (LDS-bounded)

// ---- workspace layout (bytes) ----
constexpr size_t SZ_FCSUM  = (size_t)128 * 513 * 256 * 4;            // 67,239,936 (zeroed)
constexpr size_t OFF_FCSUM = 0;
constexpr size_t OFF_HX    = SZ_FCSUM;                               // poisoned 0xFF
constexpr size_t SZ_HX     = (size_t)511 * 128 * 256 * 4;            // 66,977,792
constexpr size_t OFF_GSUM  = OFF_HX + SZ_HX;
constexpr size_t SZ_GSUM   = (size_t)128 * 513 * 768 * 4;            // 201,719,808
constexpr size_t OFF_XF    = OFF_GSUM + SZ_GSUM;
constexpr size_t SZ_XF     = (size_t)512 * 128 * 256 * 4;            // 67,108,864
constexpr size_t OFF_BTH   = OFF_XF + SZ_XF;
constexpr size_t OFF_BTL   = OFF_BTH + (size_t)1024 * 512 * 2;
constexpr size_t OFF_UH    = OFF_BTL + (size_t)1024 * 512 * 2;
constexpr size_t OFF_UL    = OFF_UH + (size_t)1024 * 256 * 2;
constexpr size_t OFF_RUNS  = OFF_UL + (size_t)1024 * 256 * 2;        // 8 * 513 ints
constexpr size_t OFF_NRUN  = OFF_RUNS + (size_t)8 * 513 * 4;         // 8 ints
// total ~406 MB

DI unsigned short f2bf(float x) {  // RNE float->bf16 bits
  union { float f; uint32_t u; } v; v.f = x;
  uint32_t r = v.u + 0x7fffu + ((v.u >> 16) & 1u);
  return (unsigned short)(r >> 16);
}
DI float bf2f(unsigned short b) {
  union { uint32_t u; float f; } v; v.u = ((uint32_t)b) << 16; return v.f;
}
DI float sigm(float x) { return 1.0f / (1.0f + __expf(-x)); }
DI float tanh_fast(float x) {
  float xc = fminf(fmaxf(x, -9.0f), 9.0f);
  float e = __expf(2.0f * xc);
  return (e - 1.0f) / (e + 1.0f);
}
// validity: packed h dword has hh exponent bits[30:23] != 0xFF (|h|<=1 -> exp<=0x7F).
DI bool okd(unsigned d) { return (d & 0x7F800000u) != 0x7F800000u; }

// =============== W transpose + bf16 hi/lo split: BT[n][k], n in [0,1024) ===============
__global__ void cvt_w_kernel(const float* __restrict__ Wiou, const float* __restrict__ Wf,
                             unsigned short* __restrict__ bth, unsigned short* __restrict__ btl)
{
  int idx = blockIdx.x * 256 + threadIdx.x;  // 1024*512
  int n = idx >> 9, k = idx & 511;
  float v = (n < 768) ? Wiou[(size_t)k * 768 + n] : Wf[(size_t)k * 256 + (n - 768)];
  unsigned short h = f2bf(v);
  bth[idx] = h;
  btl[idx] = f2bf(v - bf2f(h));
}

// =============== U -> bf16 hi/lo, [col][k] layout for B-fragment loads ===============
__global__ void cvt_u_kernel(const float* __restrict__ Uiou, const float* __restrict__ Uf,
                             unsigned short* __restrict__ uh, unsigned short* __restrict__ ul)
{
  int idx = blockIdx.x * 256 + threadIdx.x;  // 1024 cols * 256 k
  int col = idx >> 8, k = idx & 255;
  float v = (col < 768) ? Uiou[(size_t)k * 768 + col] : Uf[(size_t)k * 256 + (col - 768)];
  unsigned short h = f2bf(v);
  uh[idx] = h;
  ul[idx] = f2bf(v - bf2f(h));
}

// =============== run tables: maximal intervals with no intra-run parent edges ===============
// run [a,b) valid iff min over group batches & c in [a,b) of parents[b][c] >= b.
__global__ void run_kernel(const int* __restrict__ parents, int* __restrict__ runsg,
                           int* __restrict__ nrung)
{
  __shared__ int pmin[512];
  __shared__ unsigned short rt[513];
  __shared__ int nr_sh;
  const int g = blockIdx.x, tid = threadIdx.x;
  int mn = 1 << 30;
  #pragma unroll
  for (int b = 0; b < 16; ++b) mn = min(mn, parents[(g * 16 + b) * 512 + tid]);
  pmin[tid] = mn;
  __syncthreads();
  if (tid == 0) {
    int r = 0, a = 0;
    while (a < 512) {
      rt[r++] = (unsigned short)a;
      int b = a + 1, m = pmin[a];
      while (b < 512 && (b - a) < LMAX) {
        int m2 = min(m, pmin[b]);
        if (m2 >= b + 1) { m = m2; ++b; } else break;
      }
      a = b;
    }
    rt[r] = 512;       // sentinel
    nr_sh = r;
    nrung[g] = r;
  }
  __syncthreads();
  for (int i = tid; i <= nr_sh; i += 512) runsg[g * 513 + i] = rt[i];
}

// =============== split-bf16 GEMM: gsum[b][s][iou] = inputs @ W_iou + b; xf[s][b][.] ===============
#define GLD_LDS16(gp, lp) __builtin_amdgcn_global_load_lds( \
    (const __attribute__((address_space(1))) unsigned int*)(gp), \
    (__attribute__((address_space(3))) unsigned int*)(lp), 16, 0, 0)

__global__ __launch_bounds__(256, 2)
void gemm_split_kernel(const float* __restrict__ A,
                       const unsigned short* __restrict__ BTh,
                       const unsigned short* __restrict__ BTl,
                       const float* __restrict__ biou, const float* __restrict__ bfv,
                       float* __restrict__ gsum, float* __restrict__ xf)
{
  extern __shared__ char lds[];
  unsigned short* As = (unsigned short*)lds;             // [2][128][64]
  unsigned short* Bs = (unsigned short*)(lds + 32768);   // [2][128][64]

  const int bid = blockIdx.x;
  const int ntile = bid & 7, mtile = bid >> 3;
  const int m0 = mtile * 128, n0 = ntile * 128;
  const int tid = threadIdx.x;
  const int lane = tid & 63, w = tid >> 6;
  const int wr = w >> 1, wc = w & 1;

  f32x4 acc[4][4];
  #pragma unroll
  for (int i = 0; i < 4; i++)
    #pragma unroll
    for (int jj = 0; jj < 4; jj++) acc[i][jj] = f32x4{0.f, 0.f, 0.f, 0.f};

  const int arow = tid >> 1, ahalf = tid & 1;
  float areg[32];

  auto issueA = [&](int kk0) {
    const float* g = A + (size_t)(m0 + arow) * 512 + kk0 + ahalf * 32;
    #pragma unroll
    for (int i = 0; i < 8; i++) {
      f32x4 v = ((const f32x4*)g)[i];
      areg[i * 4 + 0] = v[0]; areg[i * 4 + 1] = v[1];
      areg[i * 4 + 2] = v[2]; areg[i * 4 + 3] = v[3];
    }
  };
  auto writeA = [&](int buf, int low) {
    unsigned short* dst = As + buf * 8192 + arow * 64 + ahalf * 32;
    #pragma unroll
    for (int i = 0; i < 4; i++) {
      u16x8 o;
      #pragma unroll
      for (int jj = 0; jj < 8; jj++) {
        float x = areg[i * 8 + jj];
        unsigned short h = f2bf(x);
        o[jj] = low ? f2bf(x - bf2f(h)) : h;
      }
      *(u16x8*)(dst + i * 8) = o;
    }
  };
  auto stageB = [&](int buf, const unsigned short* Bbase, int kk0) {
    #pragma unroll
    for (int q = 0; q < 4; q++) {
      int cidx = q * 256 + tid;
      int row = cidx >> 3, blk = cidx & 7;
      const unsigned short* g = Bbase + (size_t)(n0 + row) * 512 + kk0 + blk * 8;
      unsigned short* l = Bs + buf * 8192 + cidx * 8;
      GLD_LDS16(g, l);
    }
  };
  auto alow = [](int t) { return ((t >> 3) == 1) ? 1 : 0; };

  issueA(0);
  stageB(0, BTh, 0);
  asm volatile("s_waitcnt vmcnt(0)" ::: "memory");
  writeA(0, alow(0));
  __syncthreads();

  for (int t = 0; t < 24; ++t) {
    const int buf = t & 1;
    if (t < 23) {
      const int tn = t + 1;
      issueA((tn & 7) * 64);
      stageB(buf ^ 1, (tn < 16) ? BTh : BTl, (tn & 7) * 64);
    }
    #pragma unroll
    for (int kk = 0; kk < 64; kk += 32) {
      const int k8 = (lane >> 4) * 8;
      bf16x8 af[4], bfrag[4];
      #pragma unroll
      for (int mi = 0; mi < 4; ++mi)
        af[mi] = *(const bf16x8*)(As + buf * 8192 + (size_t)(wr * 64 + mi * 16 + (lane & 15)) * 64 + kk + k8);
      #pragma unroll
      for (int ni = 0; ni < 4; ++ni)
        bfrag[ni] = *(const bf16x8*)(Bs + buf * 8192 + (size_t)(wc * 64 + ni * 16 + (lane & 15)) * 64 + kk + k8);
      #pragma unroll
      for (int mi = 0; mi < 4; ++mi)
        #pragma unroll
        for (int ni = 0; ni < 4; ++ni)
          acc[mi][ni] = __builtin_amdgcn_mfma_f32_16x16x32_bf16(af[mi], bfrag[ni], acc[mi][ni], 0, 0, 0);
    }
    if (t < 23) {
      asm volatile("s_waitcnt vmcnt(0)" ::: "memory");
      writeA(buf ^ 1, alow(t + 1));
    }
    __syncthreads();
  }

  const bool isiou = (n0 < 768);  // block-uniform
  const int s_ = mtile;           // one s per m-tile (128 rows = all batches)
  #pragma unroll
  for (int ni = 0; ni < 4; ++ni) {
    int coln = n0 + wc * 64 + ni * 16 + (lane & 15);
    float bv = isiou ? biou[coln] : bfv[coln - 768];
    #pragma unroll
    for (int mi = 0; mi < 4; ++mi)
      #pragma unroll
      for (int r = 0; r < 4; ++r) {
        int bg = wr * 64 + mi * 16 + (lane >> 4) * 4 + r;
        float v = acc[mi][ni][r] + bv;
        if (isiou) gsum[((size_t)bg * 513 + s_) * 768 + coln] = v;
        else       xf[((size_t)s_ * 128 + bg) * 256 + (coln - 768)] = v;
      }
  }
}

// =============== scan by RUNS: 8 groups x 16 batches; 8 col-split wgs ===============
// A run [a,b) has NO intra-run parent edges (by construction), so all its nodes'
// gsum rows are final before the run starts and all L activations are parallel.
// One data-poll exchange per RUN (~90-130 total) instead of per node (512).
// Per iteration: poll+stage prev run's h blocks -> MFMA+scatter (global WGP
// atomics; no correction buffers needed) -> one vmcnt(0)+barrier -> batched
// activation + publish of current run.
__global__ __launch_bounds__(512, 1)
void scan_kernel(const unsigned short* __restrict__ ubh, const unsigned short* __restrict__ ubl,
                 const float* __restrict__ xf, const int* __restrict__ parents,
                 float* gsum, float* fcsum, unsigned* hx,
                 const int* __restrict__ runsg, const int* __restrict__ nrung,
                 float* __restrict__ out)
{
  extern __shared__ char lds[];
  unsigned short* AH  = (unsigned short*)lds;                       // [LMAX][4096]
  unsigned short* AL  = (unsigned short*)(lds + LMAX * 8192);       // [LMAX][4096]
  float*          cbuf = (float*)(lds + LMAX * 16384);              // [LMAX][16][32]
  unsigned short* rtab = (unsigned short*)(lds + LMAX * 16384 + LMAX * 2048); // [513]

  const int bid = blockIdx.x;
  const int g = bid & 7, j = bid >> 3;
  const int tid = threadIdx.x;
  const int lane = tid & 63, w = tid >> 6;
  const int gb = g * 16;

  const int NR = nrung[g];
  for (int i = tid; i <= NR; i += 512) rtab[i] = (unsigned short)runsg[g * 513 + i];

  // ---- B-frag preload: wave w -> gate w>>1, col-half w&1 (16 cols) ----
  const int colb = (w >> 1) * 256 + j * 32 + (w & 1) * 16;
  const int bcol = colb + (lane & 15);
  const int bk8 = (lane >> 4) * 8;
  bf16x8 BH[8], BL[8];
  #pragma unroll
  for (int kc = 0; kc < 8; ++kc) {
    BH[kc] = *(const bf16x8*)(ubh + (size_t)bcol * 256 + kc * 32 + bk8);
    BL[kc] = *(const bf16x8*)(ubl + (size_t)bcol * 256 + kc * 32 + bk8);
  }

  // staging ids: thread -> (kc, lane-slot) -> (batch, k0)
  const int skc = tid >> 6, sl = tid & 63;
  const int sb = sl & 15, sk0 = skc * 32 + (sl >> 4) * 8;
  // activation ids
  const int ab = tid >> 5, ahc = tid & 31;
  const int abs_b = gb + ab, acol = j * 32 + ahc;
  // scatter/f ids
  const bool isf = (w >= 6);
  const int fr0 = (lane >> 4) * 4;
  const int fcl = (w & 1) * 16 + (lane & 15);
  const int colg = colb + (lane & 15);   // iou global col
  __syncthreads();

  int pa = 0, Lp = 0;   // previous run [pa, pa+Lp)

  #pragma unroll 1
  for (int r = 0; r < NR; ++r) {
    const int a = rtab[r], bnd = rtab[r + 1];
    const int L = bnd - a;

    // ---- poll + stage prev run's h blocks (data-poll: poison 0xFF invalid) ----
    if (r > 0) {
      #pragma unroll 1
      for (int i = 0; i < Lp; ++i) {
        const unsigned* src = hx + ((size_t)(pa + i) * 8 + g) * 4096 + sb * 256 + sk0;
        u32x4 r0, r1;
        for (;;) {
          asm volatile("global_load_dwordx4 %0, %2, off sc0 sc1\n\t"
                       "global_load_dwordx4 %1, %3, off sc0 sc1\n\t"
                       "s_waitcnt vmcnt(0)"
                       : "=&v"(r0), "=&v"(r1)
                       : "v"(src), "v"(src + 4)
                       : "memory");
          bool ok = true;
          #pragma unroll
          for (int q = 0; q < 4; ++q) ok = ok && okd(r0[q]) && okd(r1[q]);
          if (__all(ok)) break;
        }
        u16x8 hiv, lov;
        #pragma unroll
        for (int q = 0; q < 4; ++q) {
          hiv[q]     = (unsigned short)(r0[q] >> 16);
          lov[q]     = (unsigned short)(r0[q] & 0xffffu);
          hiv[4 + q] = (unsigned short)(r1[q] >> 16);
          lov[4 + q] = (unsigned short)(r1[q] & 0xffffu);
        }
        *(u16x8*)(AH + i * 4096 + skc * 512 + sl * 8) = hiv;
        *(u16x8*)(AL + i * 4096 + skc * 512 + sl * 8) = lov;
      }
    }
    __syncthreads();

    // ---- phase B: each prev-run node's h @ U, scatter to parents (all >= a) ----
    if (r > 0) {
      #pragma unroll 1
      for (int i = 0; i < Lp; ++i) {
        const int c = pa + i;
        f32x4 a0 = {0.f, 0.f, 0.f, 0.f};
        f32x4 a1 = {0.f, 0.f, 0.f, 0.f};
        f32x4 a2 = {0.f, 0.f, 0.f, 0.f};
        #pragma unroll
        for (int kc = 0; kc < 8; ++kc) {
          bf16x8 ah = *(const bf16x8*)(AH + i * 4096 + kc * 512 + lane * 8);
          bf16x8 al = *(const bf16x8*)(AL + i * 4096 + kc * 512 + lane * 8);
          a0 = __builtin_amdgcn_mfma_f32_16x16x32_bf16(ah, BH[kc], a0, 0, 0, 0);
          a1 = __builtin_amdgcn_mfma_f32_16x16x32_bf16(al, BH[kc], a1, 0, 0, 0);
          a2 = __builtin_amdgcn_mfma_f32_16x16x32_bf16(ah, BL[kc], a2, 0, 0, 0);
        }
        f32x4 acc = a0 + a1 + a2;
        if (!isf) {
          #pragma unroll
          for (int q = 0; q < 4; ++q) {
            int rb = fr0 + q;
            int p = parents[(gb + rb) * 512 + c];   // p >= bnd of prev run >= a; row 512 = trash
            __hip_atomic_fetch_add(&gsum[((size_t)(gb + rb) * 513 + p) * 768 + colg],
                                   acc[q], RLX, WGP);
          }
        } else {
          #pragma unroll
          for (int q = 0; q < 4; ++q) {
            int rb = fr0 + q;
            int p = parents[(gb + rb) * 512 + c];
            float xfv = (p < 512) ? xf[((size_t)p * 128 + (gb + rb)) * 256 + j * 32 + fcl] : 0.f;
            float fg = sigm(xfv + acc[q]);
            float fc = fg * cbuf[i * 512 + rb * 32 + fcl];
            __hip_atomic_fetch_add(&fcsum[((size_t)(gb + rb) * 513 + p) * 256 + j * 32 + fcl],
                                   fc, RLX, WGP);
          }
        }
      }
    }

    // ---- single drain per RUN: scatters into rows [a,bnd) complete (wg-private cols) ----
    asm volatile("s_waitcnt vmcnt(0)" ::: "memory");
    __syncthreads();

    // ---- batched activation for current run (independent nodes); publish ----
    {
      float gi_[LMAX], go_[LMAX], gu_[LMAX], fp_[LMAX];
      #pragma unroll
      for (int i = 0; i < LMAX; ++i) {
        if (i < L) {
          size_t gio = ((size_t)abs_b * 513 + (a + i)) * 768 + acol;
          gi_[i] = gsum[gio];
          go_[i] = gsum[gio + 256];
          gu_[i] = gsum[gio + 512];
          fp_[i] = fcsum[((size_t)abs_b * 513 + (a + i)) * 256 + acol];
        }
      }
      #pragma unroll
      for (int i = 0; i < LMAX; ++i) {
        if (i < L) {
          const int s = a + i;
          float cval = sigm(gi_[i]) * tanh_fast(gu_[i]) + fp_[i];
          float h = sigm(go_[i]) * tanh_fast(cval);
          cbuf[i * 512 + ab * 32 + ahc] = cval;
          if (s < 511) {
            unsigned short hh = f2bf(h);
            unsigned short hl = f2bf(h - bf2f(hh));
            unsigned packed = ((unsigned)hh << 16) | hl;
            __hip_atomic_store(&hx[((size_t)s * 8 + g) * 4096 + ab * 256 + acol],
                               packed, RLX, AGT);
          }
          out[((size_t)s * 128 + abs_b) * 256 + acol] = h;
          if (s == 511) out[(size_t)512 * 128 * 256 + (size_t)abs_b * 256 + acol] = h;
        }
      }
    }
    pa = a; Lp = L;
    // no trailing barrier: next iteration's stage writes (AH/AL) are fenced by the
    // stage __syncthreads(); cbuf reads in next phase B follow that barrier too.
  }
}

extern "C" void kernel_launch(void* const* d_in, const int* in_sizes, int n_in,
                              void* d_out, int out_size, void* d_ws, size_t ws_size,
                              hipStream_t stream)
{
  (void)in_sizes; (void)n_in; (void)out_size; (void)ws_size;
  const float* inputs  = (const float*)d_in[0];
  const int*   parents = (const int*)d_in[1];
  const float* Wiou    = (const float*)d_in[2];
  const float* biou    = (const float*)d_in[3];
  const float* Uiou    = (const float*)d_in[4];
  const float* Wf      = (const float*)d_in[5];
  const float* bf_     = (const float*)d_in[6];
  const float* Uf      = (const float*)d_in[7];
  float* out = (float*)d_out;
  char* ws = (char*)d_ws;

  float* fcsum = (float*)(ws + OFF_FCSUM);
  unsigned* hx = (unsigned*)(ws + OFF_HX);
  float* gsum  = (float*)(ws + OFF_GSUM);
  float* xf    = (float*)(ws + OFF_XF);
  unsigned short* bth = (unsigned short*)(ws + OFF_BTH);
  unsigned short* btl = (unsigned short*)(ws + OFF_BTL);
  unsigned short* uh  = (unsigned short*)(ws + OFF_UH);
  unsigned short* ul  = (unsigned short*)(ws + OFF_UL);
  int* runsg = (int*)(ws + OFF_RUNS);
  int* nrung = (int*)(ws + OFF_NRUN);

  hipMemsetAsync(ws + OFF_FCSUM, 0, SZ_FCSUM, stream);      // fcsum zeros
  hipMemsetAsync(ws + OFF_HX, 0xFF, SZ_HX, stream);         // hx poison (invalid exponent)

  hipFuncSetAttribute((const void*)gemm_split_kernel,
                      hipFuncAttributeMaxDynamicSharedMemorySize, 65536);
  hipFuncSetAttribute((const void*)scan_kernel,
                      hipFuncAttributeMaxDynamicSharedMemorySize, 150528);

  cvt_w_kernel<<<2048, 256, 0, stream>>>(Wiou, Wf, bth, btl);
  cvt_u_kernel<<<1024, 256, 0, stream>>>(Uiou, Uf, uh, ul);
  run_kernel<<<8, 512, 0, stream>>>(parents, runsg, nrung);
  gemm_split_kernel<<<4096, 256, 65536, stream>>>(inputs, bth, btl, biou, bf_, gsum, xf);
  scan_kernel<<<64, 512, 150528, stream>>>(uh, ul, xf, parents, gsum, fcsum, hx,
                                           runsg, nrung, out);
}

// Round 12
// 2063.159 us; speedup vs baseline: 1.6584x; 1.6584x over previous
//
#include <hip/hip_runtime.h>
#include <hip/hip_bf16.h>
#include <cstdint>
#include <cstddef>

#define DI __device__ __forceinline__
#define RLX __ATOMIC_RELAXED
#define AGT __HIP_MEMORY_SCOPE_AGENT
#define WGP __HIP_MEMORY_SCOPE_WORKGROUP

typedef __attribute__((ext_vector_type(8))) short          bf16x8;
typedef __attribute__((ext_vector_type(8))) unsigned short u16x8;
typedef __attribute__((ext_vector_type(4))) unsigned short u16x4;
typedef __attribute__((ext_vector_type(4))) float          f32x4;

// ---- problem constants ----
constexpr int Sv = 512, Bv = 128, Dv = 512, Hv = 256;

// ---- workspace layout (bytes) ----
constexpr size_t SZ_FCSUM  = (size_t)128 * 513 * 256 * 4;            // 67,239,936 (zeroed AFTER gemm)
constexpr size_t OFF_FCSUM = 0;
constexpr size_t OFF_HX    = SZ_FCSUM;                               // poisoned 0xFF AFTER gemm
constexpr size_t SZ_HX     = (size_t)511 * 128 * 256 * 4;            // 66,977,792
constexpr size_t OFF_GSUM  = OFF_HX + SZ_HX;                         // 134,217,728
constexpr size_t SZ_GSUM   = (size_t)128 * 513 * 768 * 4;            // 201,719,808
constexpr size_t OFF_XF    = OFF_GSUM + SZ_GSUM;
constexpr size_t SZ_XF     = (size_t)512 * 128 * 256 * 4;            // 67,108,864
constexpr size_t OFF_BTH   = OFF_XF + SZ_XF;
constexpr size_t OFF_BTL   = OFF_BTH + (size_t)1024 * 512 * 2;
constexpr size_t OFF_UH    = OFF_BTL + (size_t)1024 * 512 * 2;
constexpr size_t OFF_UL    = OFF_UH + (size_t)1024 * 256 * 2;
// A pre-split buffers ALIAS the fcsum+hx region (exactly 128 MiB combined).
// They are live only from cvt_a to end of gemm; the fcsum/hx memsets run after.
constexpr size_t OFF_ATH   = 0;
constexpr size_t SZ_ATH    = (size_t)65536 * 512 * 2;                // 67,108,864
constexpr size_t OFF_ATL   = OFF_ATH + SZ_ATH;                       // ends at OFF_GSUM exactly

DI unsigned short f2bf(float x) {  // RNE float->bf16 bits
  union { float f; uint32_t u; } v; v.f = x;
  uint32_t r = v.u + 0x7fffu + ((v.u >> 16) & 1u);
  return (unsigned short)(r >> 16);
}
DI float bf2f(unsigned short b) {
  union { uint32_t u; float f; } v; v.u = ((uint32_t)b) << 16; return v.f;
}
DI float sigm(float x) { return 1.0f / (1.0f + __expf(-x)); }
DI float tanh_fast(float x) {   // clamp + rational exp: |err| ~1e-7, no branches
  float xc = fminf(fmaxf(x, -9.0f), 9.0f);
  float e = __expf(2.0f * xc);
  return (e - 1.0f) / (e + 1.0f);
}
// validity: packed h dword has hh exponent bits[30:23] != 0xFF (|h|<=1 -> exp<=0x7F).
DI bool okd(unsigned d) { return (d & 0x7F800000u) != 0x7F800000u; }
DI bool ok64(unsigned long long v) { return okd((unsigned)v) && okd((unsigned)(v >> 32)); }

// =============== W transpose + bf16 hi/lo split: BT[n][k], n in [0,1024) ===============
__global__ void cvt_w_kernel(const float* __restrict__ Wiou, const float* __restrict__ Wf,
                             unsigned short* __restrict__ bth, unsigned short* __restrict__ btl)
{
  int idx = blockIdx.x * 256 + threadIdx.x;  // 1024*512
  int n = idx >> 9, k = idx & 511;
  float v = (n < 768) ? Wiou[(size_t)k * 768 + n] : Wf[(size_t)k * 256 + (n - 768)];
  unsigned short h = f2bf(v);
  bth[idx] = h;
  btl[idx] = f2bf(v - bf2f(h));
}

// =============== U -> bf16 hi/lo, [col][k] layout for B-fragment loads ===============
__global__ void cvt_u_kernel(const float* __restrict__ Uiou, const float* __restrict__ Uf,
                             unsigned short* __restrict__ uh, unsigned short* __restrict__ ul)
{
  int idx = blockIdx.x * 256 + threadIdx.x;  // 1024 cols * 256 k
  int col = idx >> 8, k = idx & 255;
  float v = (col < 768) ? Uiou[(size_t)k * 768 + col] : Uf[(size_t)k * 256 + (col - 768)];
  unsigned short h = f2bf(v);
  uh[idx] = h;
  ul[idx] = f2bf(v - bf2f(h));
}

// =============== A -> bf16 hi/lo, row-major [m][k] (vectorized x4) ===============
__global__ void cvt_a_kernel(const float* __restrict__ A,
                             unsigned short* __restrict__ ath, unsigned short* __restrict__ atl)
{
  int idx = blockIdx.x * 256 + threadIdx.x;   // 8,388,608 threads x 4 elems
  f32x4 v = ((const f32x4*)A)[idx];
  u16x4 h, l;
  #pragma unroll
  for (int q = 0; q < 4; ++q) {
    h[q] = f2bf(v[q]);
    l[q] = f2bf(v[q] - bf2f(h[q]));
  }
  ((u16x4*)ath)[idx] = h;
  ((u16x4*)atl)[idx] = l;
}

// =============== split-bf16 GEMM (m97 structure: all staging via global_load_lds) ===============
// gsum[b][s][iou] = inputs @ W_iou + b; xf[s][b][.] = inputs @ W_f + b_f
// 3 terms: t 0-7 (Ah,Bh), 8-15 (Al,Bh), 16-23 (Ah,Bl); k0 = (t&7)*64.
#define GLD_LDS16(gp, lp) __builtin_amdgcn_global_load_lds( \
    (const __attribute__((address_space(1))) unsigned int*)(gp), \
    (__attribute__((address_space(3))) unsigned int*)(lp), 16, 0, 0)

__global__ __launch_bounds__(256, 2)
void gemm_split_kernel(const unsigned short* __restrict__ ATh,
                       const unsigned short* __restrict__ ATl,
                       const unsigned short* __restrict__ BTh,
                       const unsigned short* __restrict__ BTl,
                       const float* __restrict__ biou, const float* __restrict__ bfv,
                       float* __restrict__ gsum, float* __restrict__ xf)
{
  extern __shared__ char lds[];
  unsigned short* As = (unsigned short*)lds;             // [2][128][64]
  unsigned short* Bs = (unsigned short*)(lds + 32768);   // [2][128][64]

  const int bid = blockIdx.x;
  const int ntile = bid & 7, mtile = bid >> 3;
  const int m0 = mtile * 128, n0 = ntile * 128;
  const int tid = threadIdx.x;
  const int lane = tid & 63, w = tid >> 6;
  const int wr = w >> 1, wc = w & 1;

  f32x4 acc[4][4];
  #pragma unroll
  for (int i = 0; i < 4; i++)
    #pragma unroll
    for (int jj = 0; jj < 4; jj++) acc[i][jj] = f32x4{0.f, 0.f, 0.f, 0.f};

  auto stage = [&](unsigned short* dstbase, const unsigned short* src0,
                   int row0, int kk0, int buf) {
    #pragma unroll
    for (int q = 0; q < 4; ++q) {
      int cidx = q * 256 + tid;
      int row = cidx >> 3, blk = cidx & 7;
      const unsigned short* gp = src0 + (size_t)(row0 + row) * 512 + kk0 + blk * 8;
      unsigned short* lp = dstbase + buf * 8192 + cidx * 8;
      GLD_LDS16(gp, lp);
    }
  };

  stage(As, ATh, m0, 0, 0);
  stage(Bs, BTh, n0, 0, 0);
  asm volatile("s_waitcnt vmcnt(0)" ::: "memory");
  __syncthreads();

  for (int t = 0; t < 24; ++t) {
    const int buf = t & 1;
    if (t < 23) {
      const int tn = t + 1;
      stage(As, (tn >= 8 && tn < 16) ? ATl : ATh, m0, (tn & 7) * 64, buf ^ 1);
      stage(Bs, (tn < 16) ? BTh : BTl, n0, (tn & 7) * 64, buf ^ 1);
    }
    #pragma unroll
    for (int kk = 0; kk < 64; kk += 32) {
      const int k8 = (lane >> 4) * 8;
      bf16x8 af[4], bfrag[4];
      #pragma unroll
      for (int mi = 0; mi < 4; ++mi)
        af[mi] = *(const bf16x8*)(As + buf * 8192 + (size_t)(wr * 64 + mi * 16 + (lane & 15)) * 64 + kk + k8);
      #pragma unroll
      for (int ni = 0; ni < 4; ++ni)
        bfrag[ni] = *(const bf16x8*)(Bs + buf * 8192 + (size_t)(wc * 64 + ni * 16 + (lane & 15)) * 64 + kk + k8);
      #pragma unroll
      for (int mi = 0; mi < 4; ++mi)
        #pragma unroll
        for (int ni = 0; ni < 4; ++ni)
          acc[mi][ni] = __builtin_amdgcn_mfma_f32_16x16x32_bf16(af[mi], bfrag[ni], acc[mi][ni], 0, 0, 0);
    }
    asm volatile("s_waitcnt vmcnt(0)" ::: "memory");
    __syncthreads();
  }

  const bool isiou = (n0 < 768);  // block-uniform
  const int s_ = mtile;           // one s per m-tile (128 rows = all batches)
  #pragma unroll
  for (int ni = 0; ni < 4; ++ni) {
    int coln = n0 + wc * 64 + ni * 16 + (lane & 15);
    float bv = isiou ? biou[coln] : bfv[coln - 768];
    #pragma unroll
    for (int mi = 0; mi < 4; ++mi)
      #pragma unroll
      for (int r = 0; r < 4; ++r) {
        int bg = wr * 64 + mi * 16 + (lane >> 4) * 4 + r;
        float v = acc[mi][ni][r] + bv;
        if (isiou) gsum[((size_t)bg * 513 + s_) * 768 + coln] = v;
        else       xf[((size_t)s_ * 128 + bg) * 256 + (coln - 768)] = v;
      }
  }
}

// =============== scan (R7 structure, verified 1752 us): 8 groups x 16 batches ===============
// Data-poll exchange (no flags, hang-safe): h published per-step into poisoned hx
// slots; readers poll the data itself. gsum/fcsum/xf wg-private (WGP atomics, plain
// prefetch loads). Only change vs R7: tanhf -> tanh_fast.
__global__ __launch_bounds__(512, 1)
void scan_kernel(const unsigned short* __restrict__ ubh, const unsigned short* __restrict__ ubl,
                 const float* __restrict__ xf, const int* __restrict__ parents,
                 float* gsum, float* fcsum, unsigned* hx,
                 float* __restrict__ out)
{
  __shared__ __align__(16) unsigned short AH[8 * 64 * 8];   // A-frags hi: [kc][lane][8]
  __shared__ __align__(16) unsigned short AL[8 * 64 * 8];   // A-frags lo
  __shared__ float gcor[16 * 96];
  __shared__ float fcor[16 * 32];
  __shared__ float cbuf[16 * 32];
  __shared__ int   pbuf[2][16];
  __shared__ int   pl[16];

  const int bid = blockIdx.x;
  const int g = bid & 7, j = bid >> 3;   // group spread: members share bid%8
  const int tid = threadIdx.x;
  const int lane = tid & 63, w = tid >> 6;
  const int gb = g * 16;

  // ---- B-frag preload: wave w -> gate w>>1, col-half w&1 (16 cols) ----
  const int colb = (w >> 1) * 256 + j * 32 + (w & 1) * 16;
  const int bcol = colb + (lane & 15);
  const int bk8 = (lane >> 4) * 8;
  bf16x8 BH[8], BL[8];
  #pragma unroll
  for (int kc = 0; kc < 8; ++kc) {
    BH[kc] = *(const bf16x8*)(ubh + (size_t)bcol * 256 + kc * 32 + bk8);
    BL[kc] = *(const bf16x8*)(ubl + (size_t)bcol * 256 + kc * 32 + bk8);
  }

  // staging ids: thread -> (kc, lane-slot) -> (batch, k0)
  const int skc = tid >> 6, sl = tid & 63;
  const int sb = sl & 15, sk0 = skc * 32 + (sl >> 4) * 8;
  // activation ids
  const int ab = tid >> 5, ahc = tid & 31;
  const int abs_b = gb + ab, acol = j * 32 + ahc;
  // f ids
  const bool isf = (w >= 6);
  const int fr0 = (lane >> 4) * 4;
  const int fcl = (w & 1) * 16 + (lane & 15);

  if (tid < 16) { pbuf[0][tid] = parents[(gb + tid) * 512]; pl[tid] = -1; }

  float pre_i, pre_o, pre_u, fct_pre;
  {
    size_t gi0 = ((size_t)abs_b * 513) * 768 + acol;
    pre_i = gsum[gi0];
    pre_o = gsum[gi0 + 256];
    pre_u = gsum[gi0 + 512];
    fct_pre = fcsum[((size_t)abs_b * 513) * 256 + acol];
  }
  float xfv[4] = {0.f, 0.f, 0.f, 0.f};
  __syncthreads();

  #pragma unroll 1
  for (int s = 0; s < 512; ++s) {
    // ---- stage h(s-1): DATA-POLL per-step slot, unpack to AH/AL frag layout ----
    if (s > 0) {
      const unsigned long long* s64 =
          (const unsigned long long*)(hx + ((size_t)(s - 1) * 8 + g) * 4096 + sb * 256 + sk0);
      unsigned long long v0, v1, v2, v3;
      for (;;) {
        v0 = __hip_atomic_load(s64 + 0, RLX, AGT);
        v1 = __hip_atomic_load(s64 + 1, RLX, AGT);
        v2 = __hip_atomic_load(s64 + 2, RLX, AGT);
        v3 = __hip_atomic_load(s64 + 3, RLX, AGT);
        if (ok64(v0) && ok64(v1) && ok64(v2) && ok64(v3)) break;
      }
      u16x8 hiv, lov;
      unsigned long long vv[4] = {v0, v1, v2, v3};
      #pragma unroll
      for (int q = 0; q < 4; ++q) {
        unsigned lo32 = (unsigned)vv[q], hi32 = (unsigned)(vv[q] >> 32);
        hiv[2 * q]     = (unsigned short)(lo32 >> 16);
        lov[2 * q]     = (unsigned short)(lo32 & 0xffffu);
        hiv[2 * q + 1] = (unsigned short)(hi32 >> 16);
        lov[2 * q + 1] = (unsigned short)(hi32 & 0xffffu);
      }
      *(u16x8*)(AH + skc * 512 + sl * 8) = hiv;
      *(u16x8*)(AL + skc * 512 + sl * 8) = lov;
    }
    __syncthreads();   // stage barrier

    // ---- phase B: h(s-1) @ U (all 4 gates, 3-term split, 3 independent MFMA chains) ----
    if (s > 0) {
      f32x4 a0 = {0.f, 0.f, 0.f, 0.f};
      f32x4 a1 = {0.f, 0.f, 0.f, 0.f};
      f32x4 a2 = {0.f, 0.f, 0.f, 0.f};
      #pragma unroll
      for (int kc = 0; kc < 8; ++kc) {
        bf16x8 ah = *(const bf16x8*)(AH + kc * 512 + lane * 8);
        bf16x8 al = *(const bf16x8*)(AL + kc * 512 + lane * 8);
        a0 = __builtin_amdgcn_mfma_f32_16x16x32_bf16(ah, BH[kc], a0, 0, 0, 0);
        a1 = __builtin_amdgcn_mfma_f32_16x16x32_bf16(al, BH[kc], a1, 0, 0, 0);
        a2 = __builtin_amdgcn_mfma_f32_16x16x32_bf16(ah, BL[kc], a2, 0, 0, 0);
      }
      f32x4 acc = a0 + a1 + a2;
      if (!isf) {
        const int colg = colb + (lane & 15);
        const int colL = (w >> 1) * 32 + (w & 1) * 16 + (lane & 15);
        #pragma unroll
        for (int r = 0; r < 4; ++r) {
          int rb = fr0 + r;
          int p = pbuf[(s - 1) & 1][rb];
          if (p == s) gcor[rb * 96 + colL] = acc[r];
          else __hip_atomic_fetch_add(&gsum[((size_t)(gb + rb) * 513 + p) * 768 + colg],
                                      acc[r], RLX, WGP);   // wg-private: local-L2 atomic
        }
      } else {
        #pragma unroll
        for (int r = 0; r < 4; ++r) {
          int rb = fr0 + r;
          int p = pbuf[(s - 1) & 1][rb];
          float fg = sigm(xfv[r] + acc[r]);
          float fc = fg * cbuf[rb * 32 + fcl];
          if (p == s) fcor[rb * 32 + fcl] = fc;
          else __hip_atomic_fetch_add(&fcsum[((size_t)(gb + rb) * 513 + p) * 256 + j * 32 + fcl],
                                      fc, RLX, WGP);       // wg-private: local-L2 atomic
        }
        if (w == 6 && (lane & 15) == 0) {
          #pragma unroll
          for (int r = 0; r < 4; ++r) pl[fr0 + r] = pbuf[(s - 1) & 1][fr0 + r];
        }
      }
    }

    // ---- drain scatters (wg-local), then barrier: orders scatters/gcor/pl vs below ----
    asm volatile("s_waitcnt vmcnt(0)" ::: "memory");
    __syncthreads();

    // ---- activation for node s (all 512 threads: 16 b x 32 hc); publish h FIRST ----
    {
      bool corr = (pl[ab] == s);
      float gi = pre_i + (corr ? gcor[ab * 96 + ahc] : 0.f);
      float go = pre_o + (corr ? gcor[ab * 96 + 32 + ahc] : 0.f);
      float gu = pre_u + (corr ? gcor[ab * 96 + 64 + ahc] : 0.f);
      float fct = fct_pre + (corr ? fcor[ab * 32 + ahc] : 0.f);
      float c = sigm(gi) * tanh_fast(gu) + fct;
      float h = sigm(go) * tanh_fast(c);
      if (s < 511) {
        unsigned short hh = f2bf(h);
        unsigned short hl = f2bf(h - bf2f(hh));
        unsigned packed = ((unsigned)hh << 16) | hl;
        __hip_atomic_store(&hx[((size_t)s * 8 + g) * 4096 + ab * 256 + acol],
                           packed, RLX, AGT);   // coherence point: readers data-poll this
      }
      cbuf[ab * 32 + ahc] = c;
      out[((size_t)s * 128 + abs_b) * 256 + acol] = h;
      if (s == 511) out[(size_t)512 * 128 * 256 + (size_t)abs_b * 256 + acol] = h;
    }

    // ---- prefetch row s+1 (wg-private; ordered after this step's scatters by the
    //      drain barrier above) — overlaps the next stage poll ----
    if (s < 511) {
      const int sn = s + 1;
      {
        size_t gi1 = ((size_t)abs_b * 513 + sn) * 768 + acol;
        pre_i = gsum[gi1];
        pre_o = gsum[gi1 + 256];
        pre_u = gsum[gi1 + 512];
        fct_pre = fcsum[((size_t)abs_b * 513 + sn) * 256 + acol];
      }
      if (tid < 16) pbuf[sn & 1][tid] = parents[(gb + tid) * 512 + sn];
      if (isf) {
        #pragma unroll
        for (int r = 0; r < 4; ++r) {
          int p = pbuf[s & 1][fr0 + r];   // parents[.][s], loaded last iteration
          xfv[r] = (p < 512) ? xf[((size_t)p * 128 + (gb + fr0 + r)) * 256 + j * 32 + fcl] : 0.f;
        }
      }
    }
  }
}

extern "C" void kernel_launch(void* const* d_in, const int* in_sizes, int n_in,
                              void* d_out, int out_size, void* d_ws, size_t ws_size,
                              hipStream_t stream)
{
  (void)in_sizes; (void)n_in; (void)out_size; (void)ws_size;
  const float* inputs  = (const float*)d_in[0];
  const int*   parents = (const int*)d_in[1];
  const float* Wiou    = (const float*)d_in[2];
  const float* biou    = (const float*)d_in[3];
  const float* Uiou    = (const float*)d_in[4];
  const float* Wf      = (const float*)d_in[5];
  const float* bf_     = (const float*)d_in[6];
  const float* Uf      = (const float*)d_in[7];
  float* out = (float*)d_out;
  char* ws = (char*)d_ws;

  float* fcsum = (float*)(ws + OFF_FCSUM);
  unsigned* hx = (unsigned*)(ws + OFF_HX);
  float* gsum  = (float*)(ws + OFF_GSUM);
  float* xf    = (float*)(ws + OFF_XF);
  unsigned short* bth = (unsigned short*)(ws + OFF_BTH);
  unsigned short* btl = (unsigned short*)(ws + OFF_BTL);
  unsigned short* uh  = (unsigned short*)(ws + OFF_UH);
  unsigned short* ul  = (unsigned short*)(ws + OFF_UL);
  unsigned short* ath = (unsigned short*)(ws + OFF_ATH);  // aliases fcsum+hx (pre-gemm only)
  unsigned short* atl = (unsigned short*)(ws + OFF_ATL);

  hipFuncSetAttribute((const void*)gemm_split_kernel,
                      hipFuncAttributeMaxDynamicSharedMemorySize, 65536);

  // Phase 1: precompute bf16 splits (A buffers live in the fcsum+hx alias region)
  cvt_w_kernel<<<2048, 256, 0, stream>>>(Wiou, Wf, bth, btl);
  cvt_u_kernel<<<1024, 256, 0, stream>>>(Uiou, Uf, uh, ul);
  cvt_a_kernel<<<32768, 256, 0, stream>>>(inputs, ath, atl);
  // Phase 2: input GEMM (reads ath/atl, writes gsum/xf)
  gemm_split_kernel<<<4096, 256, 65536, stream>>>(ath, atl, bth, btl, biou, bf_, gsum, xf);
  // Phase 3: scan-state init (overwrites the alias region AFTER gemm is done)
  hipMemsetAsync(ws + OFF_FCSUM, 0, SZ_FCSUM, stream);    // fcsum zeros
  hipMemsetAsync(ws + OFF_HX, 0xFF, SZ_HX, stream);       // hx poison (invalid exponent)
  // Phase 4: sequential scan
  scan_kernel<<<64, 512, 0, stream>>>(uh, ul, xf, parents, gsum, fcsum, hx, out);
}